// Round 5
// baseline (112.155 us; speedup 1.0000x reference)
//
#include <hip/hip_runtime.h>

#define NHEAD 16
#define TDIM 2048
#define SDIM 2048
#define KMAX 4

#define NELEM ((size_t)NHEAD * TDIM * SDIM)   // 67,108,864 floats
#define NBYTES (NELEM * sizeof(float))        // 256 MiB

// Decider + last-row rewrite. One block, 1024 threads = 16 waves.
// Wave h computes argmax (first-occurrence tie-break) of head h's last row
// from `in`; thread 0 does the vote/merge decision; all threads overwrite
// the 16 last rows of `out` (which the preceding full-buffer memcpy filled
// with the unmerged values). Reads only `in` -> deterministic.
__global__ void __launch_bounds__(1024)
decide_apply_kernel(const float* __restrict__ in, float* __restrict__ out) {
    __shared__ int s_cand[NHEAD];
    __shared__ int s_replace[NHEAD];
    __shared__ int s_sampled;

    const int tid  = threadIdx.x;
    const int head = tid >> 6;   // 16 waves -> 16 heads
    const int lane = tid & 63;

    const size_t last_off = (size_t)(TDIM - 1) * SDIM;

    // --- per-head argmax over S (vectorized), first-occurrence tie-break ---
    const float4* row =
        (const float4*)(in + (size_t)head * TDIM * SDIM + last_off);
    float best = -1.0f;          // inputs are uniform [0,1)
    int   bidx = 1 << 30;
    #pragma unroll
    for (int f = lane; f < SDIM / 4; f += 64) {
        float4 v = row[f];
        const int e = f * 4;
        if (v.x > best) { best = v.x; bidx = e + 0; }
        if (v.y > best) { best = v.y; bidx = e + 1; }
        if (v.z > best) { best = v.z; bidx = e + 2; }
        if (v.w > best) { best = v.w; bidx = e + 3; }
    }
    #pragma unroll
    for (int off = 32; off > 0; off >>= 1) {
        float ov = __shfl_down(best, off);
        int   oi = __shfl_down(bidx, off);
        if (ov > best || (ov == best && oi < bidx)) { best = ov; bidx = oi; }
    }
    if (lane == 0) s_cand[head] = bidx;
    __syncthreads();

    // --- serial decision on thread 0 (16x16 comparisons, trivial) ---
    if (tid == 0) {
        int cnt[NHEAD];
        int maxv = 0;
        for (int h = 0; h < NHEAD; ++h) {
            int c = 0;
            for (int g = 0; g < NHEAD; ++g) c += (s_cand[g] == s_cand[h]);
            cnt[h] = c;
            if (c > maxv) maxv = c;
        }
        int sampled = 0;
        for (int h = NHEAD - 1; h >= 0; --h)
            if (cnt[h] == maxv) sampled = h;       // first head with mask set
        const bool merge = (maxv <= KMAX);
        for (int h = 0; h < NHEAD; ++h)
            s_replace[h] = (merge && cnt[h] == maxv) ? 1 : 0;
        s_sampled = sampled;
    }
    __syncthreads();

    const int sampled = s_sampled;

    // --- rewrite the 16 last rows (vectorized float4) ---
    const int S4 = SDIM / 4;
    for (int idx = tid; idx < NHEAD * S4; idx += 1024) {
        const int h = idx >> 9;          // / S4
        const int f = idx & (S4 - 1);    // % S4
        const int src_h = s_replace[h] ? sampled : h;
        const float4* src =
            (const float4*)(in + (size_t)src_h * TDIM * SDIM + last_off);
        float4* dst = (float4*)(out + (size_t)h * TDIM * SDIM + last_off);
        dst[f] = src[f];
    }
}

extern "C" void kernel_launch(void* const* d_in, const int* in_sizes, int n_in,
                              void* d_out, int out_size, void* d_ws, size_t ws_size,
                              hipStream_t stream) {
    const float* in = (const float*)d_in[0];
    float* out = (float*)d_out;

    // Vendor blit copy of the full tensor, then overwrite the 16 last rows.
    hipMemcpyAsync(out, in, NBYTES, hipMemcpyDeviceToDevice, stream);
    decide_apply_kernel<<<1, 1024, 0, stream>>>(in, out);
}

// Round 7
// 84.377 us; speedup vs baseline: 1.3292x; 1.3292x over previous
//
#include <hip/hip_runtime.h>

#define NHEAD 16
#define TDIM 2048
#define SDIM 2048
#define KMAX 4

#define S4    (SDIM / 4)            // 512 float4 per row
#define HEAD4 (TDIM * S4)           // 1048576 float4 per head (power of 2)
#define COPY4 ((TDIM - 1) * S4)     // float4 per head excluding last row
#define N4    (NHEAD * HEAD4)       // 16777216 float4 total
#define NBLK  2048                  // exactly 8192 waves = chip capacity
#define BLKSZ 256
#define CSTRIDE ((NBLK - 1) * BLKSZ)  // copy stride: 2047 copy blocks

typedef float vf4 __attribute__((ext_vector_type(4)));  // native vector for nt builtins

// Single fused kernel, exactly-resident grid (2048 blocks x 4 waves = 8192):
//  - block 0: PURE decider (argmax/vote/merge + write the 16 last rows).
//    Starts at t=0, hides fully under the bulk copy. Reads only `in`,
//    writes only the last rows, which the copy blocks skip -> no ordering.
//  - blocks 1..2047: grid-stride vf4 copy of everything EXCEPT each
//    head's last row. Stores are NON-TEMPORAL so the 268 MB write stream
//    doesn't evict `in` from L2/L3 -> reads become L3-resident across
//    replays, HBM traffic drops toward write-only.
__global__ void __launch_bounds__(BLKSZ, 8)
fused_policy_kernel(const vf4* __restrict__ in, vf4* __restrict__ out) {
    const int tid = threadIdx.x;
    const int b   = blockIdx.x;

    if (b != 0) {
        // ---- bulk copy (blocks 1..2047), non-temporal stores ----
        unsigned i = (unsigned)(b - 1) * BLKSZ + tid;
        #pragma unroll 4
        for (; i < N4; i += CSTRIDE) {
            if ((i & (HEAD4 - 1)) < COPY4) {
                vf4 v = in[i];
                __builtin_nontemporal_store(v, &out[i]);
            }
        }
        return;
    }

    // ---- decider (block 0 only): 256 threads, 16 per head ----
    __shared__ int s_cand[NHEAD];
    __shared__ int s_replace[NHEAD];
    __shared__ int s_sampled;

    const int head = tid >> 4;
    const int l16  = tid & 15;

    const vf4* row = in + (size_t)head * HEAD4 + COPY4;  // head's last row

    // per-head argmax, first-occurrence tie-break (matches jnp.argmax)
    float best = -1.0f;           // inputs are uniform [0,1)
    int   bidx = 1 << 30;
    for (int f = l16; f < S4; f += 16) {
        vf4 v = row[f];
        const int e = f * 4;
        if (v.x > best) { best = v.x; bidx = e + 0; }
        if (v.y > best) { best = v.y; bidx = e + 1; }
        if (v.z > best) { best = v.z; bidx = e + 2; }
        if (v.w > best) { best = v.w; bidx = e + 3; }
    }
    #pragma unroll
    for (int off = 8; off > 0; off >>= 1) {
        float ov = __shfl_down(best, off, 16);
        int   oi = __shfl_down(bidx, off, 16);
        if (ov > best || (ov == best && oi < bidx)) { best = ov; bidx = oi; }
    }
    if (l16 == 0) s_cand[head] = bidx;
    __syncthreads();

    if (tid == 0) {
        int cnt[NHEAD];
        int maxv = 0;
        for (int h = 0; h < NHEAD; ++h) {
            int c = 0;
            for (int g = 0; g < NHEAD; ++g) c += (s_cand[g] == s_cand[h]);
            cnt[h] = c;
            if (c > maxv) maxv = c;
        }
        int sampled = 0;
        for (int h = NHEAD - 1; h >= 0; --h)
            if (cnt[h] == maxv) sampled = h;          // first head with mask set
        const bool merge = (maxv <= KMAX);
        for (int h = 0; h < NHEAD; ++h)
            s_replace[h] = (merge && cnt[h] == maxv) ? 1 : 0;
        s_sampled = sampled;
    }
    __syncthreads();

    const int sampled = s_sampled;

    // rewrite the 16 last rows (vectorized)
    for (int idx = tid; idx < NHEAD * S4; idx += BLKSZ) {
        const int h = idx >> 9;          // / S4
        const int f = idx & (S4 - 1);    // % S4
        const int src_h = s_replace[h] ? sampled : h;
        out[(size_t)h * HEAD4 + COPY4 + f] =
            in[(size_t)src_h * HEAD4 + COPY4 + f];
    }
}

extern "C" void kernel_launch(void* const* d_in, const int* in_sizes, int n_in,
                              void* d_out, int out_size, void* d_ws, size_t ws_size,
                              hipStream_t stream) {
    const vf4* in = (const vf4*)d_in[0];
    vf4* out = (vf4*)d_out;

    fused_policy_kernel<<<NBLK, BLKSZ, 0, stream>>>(in, out);
}